// Round 6
// baseline (131.338 us; speedup 1.0000x reference)
//
#include <hip/hip_runtime.h>

// Problem dims (fixed by reference)
#define B_DIM 32
#define N_DIM 4096
#define PATCH_DIM 1024
#define TEXT_DIM 768
#define HIDDEN 512

typedef float f32x4 __attribute__((ext_vector_type(4)));

__device__ __forceinline__ float dot4(f32x4 a, f32x4 b) {
    return a.x * b.x + a.y * b.y + a.z * b.z + a.w * b.w;
}

__device__ __forceinline__ f32x4 fma4(f32x4 a, float s, f32x4 w) {
    a.x = fmaf(s, w.x, a.x);
    a.y = fmaf(s, w.y, a.y);
    a.z = fmaf(s, w.z, a.z);
    a.w = fmaf(s, w.w, a.w);
    return a;
}

// ---------------------------------------------------------------------------
// Fused prep kernel: grid 32 (one block per b), 1024 threads (16 waves).
// Phase 1: t[b,h] = text[b]·W_text[h] + b_text[h]  -> LDS.
//   Wave w computes h in [w*32, w*32+32): wave-dot over 768 (3 f32x4/lane),
//   butterfly reduce. W_text rows fully coalesced; 1.5 MB, L2-resident.
// Phase 2: v[b,d] = sum_h t[h]*W_patch[h,d].
//   Thread (hg=tid>>8, t8=tid&255) accumulates h in [hg*128,(hg+1)*128) for
//   d = 4*t8..4*t8+3 with 8 independent f32x4 accumulator streams (16 B
//   coalesced loads, ~8 in flight -> latency hidden; the old split fold used
//   scalar 4 B loads and was the prep bottleneck). 16 KB LDS reduce across
//   the 4 h-groups.
// bias[b] = t[b,:]·b_patch via wave butterflies + LDS.
// ---------------------------------------------------------------------------
__global__ __launch_bounds__(1024) void prep_kernel(
    const float* __restrict__ text,     // [B, TEXT_DIM]
    const float* __restrict__ W_text,   // [HIDDEN, TEXT_DIM]
    const float* __restrict__ b_text,   // [HIDDEN]
    const float* __restrict__ W_patch,  // [HIDDEN, PATCH_DIM]
    const float* __restrict__ b_patch,  // [HIDDEN]
    float* __restrict__ v,              // [B, PATCH_DIM]
    float* __restrict__ bias_out)       // [B]
{
    const int b    = blockIdx.x;
    const int tid  = threadIdx.x;
    const int lane = tid & 63;
    const int wid  = tid >> 6;          // 0..15

    __shared__ float t_sh[HIDDEN];
    __shared__ f32x4 part_sh[4][256];
    __shared__ float wsum[16];

    // ---- Phase 1: t_sh ----
    const f32x4* tx4 = (const f32x4*)(text + (size_t)b * TEXT_DIM);
    const f32x4 t0 = tx4[lane], t1 = tx4[lane + 64], t2 = tx4[lane + 128];

    #pragma unroll 2
    for (int i = 0; i < 32; ++i) {
        const int h = wid * 32 + i;
        const f32x4* wr = (const f32x4*)(W_text + (size_t)h * TEXT_DIM);
        float s = dot4(t0, wr[lane]) + dot4(t1, wr[lane + 64])
                + dot4(t2, wr[lane + 128]);
        #pragma unroll
        for (int off = 32; off; off >>= 1)
            s += __shfl_xor(s, off, 64);
        if (lane == 0)
            t_sh[h] = s + b_text[h];
    }
    __syncthreads();

    // ---- Phase 2: v slice, 8 independent accumulator streams ----
    const int hg    = tid >> 8;         // 0..3
    const int t8    = tid & 255;        // 0..255 -> d0 = 4*t8
    const int hbase = hg * 128;

    f32x4 acc[8];
    #pragma unroll
    for (int k = 0; k < 8; ++k) acc[k] = (f32x4){0.f, 0.f, 0.f, 0.f};

    #pragma unroll 2
    for (int h = 0; h < 128; h += 8) {
        #pragma unroll
        for (int k = 0; k < 8; ++k) {
            const int hh = hbase + h + k;
            const f32x4 w =
                ((const f32x4*)(W_patch + (size_t)hh * PATCH_DIM))[t8];
            acc[k] = fma4(acc[k], t_sh[hh], w);
        }
    }
    f32x4 accs = ((acc[0] + acc[1]) + (acc[2] + acc[3]))
               + ((acc[4] + acc[5]) + (acc[6] + acc[7]));
    part_sh[hg][t8] = accs;
    __syncthreads();

    if (hg == 0) {
        f32x4 r = (part_sh[0][t8] + part_sh[1][t8])
                + (part_sh[2][t8] + part_sh[3][t8]);
        ((f32x4*)(v + (size_t)b * PATCH_DIM))[t8] = r;
    }

    // ---- bias[b] ----
    float partial = (tid < HIDDEN) ? t_sh[tid] * b_patch[tid] : 0.f;
    #pragma unroll
    for (int off = 32; off; off >>= 1)
        partial += __shfl_xor(partial, off, 64);
    if (lane == 0) wsum[wid] = partial;
    __syncthreads();
    if (tid == 0) {
        float s = 0.f;
        #pragma unroll
        for (int w = 0; w < 16; ++w) s += wsum[w];
        bias_out[b] = s;
    }
}

// ---------------------------------------------------------------------------
// Kernel C (dominant, streams 512 MB of patches):
//   scores[b,n] = patches[b,n,:] . v[b,:] + bias[b]
// EXACT R2 structure (proven best: 112.5 us total; every variation lost):
// 2048 blocks x 4 waves, wave owns 16 contiguous rows of one b, v[b] in 16
// regs, nontemporal loads (R5 isolated: removing nt cost ~14 us — the
// no-allocate policy protects L2 from the one-shot 512 MB stream),
// compiler-scheduled 4-row groups at ~100 VGPR / 5 waves/SIMD.
// ---------------------------------------------------------------------------
__global__ __launch_bounds__(256) void score_kernel(
    const float* __restrict__ patches,  // [B*N, PATCH_DIM]
    const float* __restrict__ v,        // [B, PATCH_DIM]
    const float* __restrict__ bias,     // [B]
    float* __restrict__ out)            // [B*N]
{
    const int lane = threadIdx.x & 63;
    const int g    = blockIdx.x * 4 + (threadIdx.x >> 6);  // 0..8191
    const int b    = g >> 8;          // 256 waves per b
    const int row0 = g << 4;          // 16 rows per wave

    const f32x4* vv = (const f32x4*)(v + (size_t)b * PATCH_DIM);
    const f32x4 v0 = vv[lane], v1 = vv[lane + 64],
                v2 = vv[lane + 128], v3 = vv[lane + 192];
    const float bs = bias[b];

    for (int i = 0; i < 16; i += 4) {
        const f32x4* p0 = (const f32x4*)(patches + (size_t)(row0 + i + 0) * PATCH_DIM);
        const f32x4* p1 = (const f32x4*)(patches + (size_t)(row0 + i + 1) * PATCH_DIM);
        const f32x4* p2 = (const f32x4*)(patches + (size_t)(row0 + i + 2) * PATCH_DIM);
        const f32x4* p3 = (const f32x4*)(patches + (size_t)(row0 + i + 3) * PATCH_DIM);

        f32x4 a00 = __builtin_nontemporal_load(p0 + lane);
        f32x4 a01 = __builtin_nontemporal_load(p0 + lane + 64);
        f32x4 a02 = __builtin_nontemporal_load(p0 + lane + 128);
        f32x4 a03 = __builtin_nontemporal_load(p0 + lane + 192);
        f32x4 a10 = __builtin_nontemporal_load(p1 + lane);
        f32x4 a11 = __builtin_nontemporal_load(p1 + lane + 64);
        f32x4 a12 = __builtin_nontemporal_load(p1 + lane + 128);
        f32x4 a13 = __builtin_nontemporal_load(p1 + lane + 192);
        f32x4 a20 = __builtin_nontemporal_load(p2 + lane);
        f32x4 a21 = __builtin_nontemporal_load(p2 + lane + 64);
        f32x4 a22 = __builtin_nontemporal_load(p2 + lane + 128);
        f32x4 a23 = __builtin_nontemporal_load(p2 + lane + 192);
        f32x4 a30 = __builtin_nontemporal_load(p3 + lane);
        f32x4 a31 = __builtin_nontemporal_load(p3 + lane + 64);
        f32x4 a32 = __builtin_nontemporal_load(p3 + lane + 128);
        f32x4 a33 = __builtin_nontemporal_load(p3 + lane + 192);

        float s0 = dot4(a00, v0) + dot4(a01, v1) + dot4(a02, v2) + dot4(a03, v3);
        float s1 = dot4(a10, v0) + dot4(a11, v1) + dot4(a12, v2) + dot4(a13, v3);
        float s2 = dot4(a20, v0) + dot4(a21, v1) + dot4(a22, v2) + dot4(a23, v3);
        float s3 = dot4(a30, v0) + dot4(a31, v1) + dot4(a32, v2) + dot4(a33, v3);

        // 4 independent butterfly chains, interleaved to hide shfl latency
        #pragma unroll
        for (int off = 32; off; off >>= 1) {
            s0 += __shfl_xor(s0, off, 64);
            s1 += __shfl_xor(s1, off, 64);
            s2 += __shfl_xor(s2, off, 64);
            s3 += __shfl_xor(s3, off, 64);
        }

        if (lane == 0) {
            f32x4 o = { s0 + bs, s1 + bs, s2 + bs, s3 + bs };
            *(f32x4*)(out + row0 + i) = o;
        }
    }
}

extern "C" void kernel_launch(void* const* d_in, const int* in_sizes, int n_in,
                              void* d_out, int out_size, void* d_ws, size_t ws_size,
                              hipStream_t stream) {
    const float* patches = (const float*)d_in[0];  // [B, N, PATCH_DIM]
    const float* text    = (const float*)d_in[1];  // [B, TEXT_DIM]
    const float* W_patch = (const float*)d_in[2];  // [HIDDEN, PATCH_DIM]
    const float* b_patch = (const float*)d_in[3];  // [HIDDEN]
    const float* W_text  = (const float*)d_in[4];  // [HIDDEN, TEXT_DIM]
    const float* b_text  = (const float*)d_in[5];  // [HIDDEN]
    float* out = (float*)d_out;                    // [B, N]

    // Workspace layout (floats): v [B*PATCH_DIM], bias [B]
    float* v_ws    = (float*)d_ws;
    float* bias_ws = v_ws + B_DIM * PATCH_DIM;

    prep_kernel<<<B_DIM, 1024, 0, stream>>>(text, W_text, b_text,
                                            W_patch, b_patch, v_ws, bias_ws);
    score_kernel<<<2048, 256, 0, stream>>>(patches, v_ws, bias_ws, out);
}

// Round 7
// 109.369 us; speedup vs baseline: 1.2009x; 1.2009x over previous
//
#include <hip/hip_runtime.h>

// Problem dims (fixed by reference)
#define B_DIM 32
#define N_DIM 4096
#define PATCH_DIM 1024
#define TEXT_DIM 768
#define HIDDEN 512

typedef float f32x4 __attribute__((ext_vector_type(4)));

__device__ __forceinline__ float dot4(f32x4 a, f32x4 b) {
    return a.x * b.x + a.y * b.y + a.z * b.z + a.w * b.w;
}

// ---------------------------------------------------------------------------
// Kernel A (R2-proven, verbatim): t[b,h] = text[b,:]·W_text[h,:] + b_text[h]
// grid (32 b, 8 h-chunks) x 256. Wave per 16 h; text row in 3 regs/lane.
// W_text rows read coalesced; spread over 256 blocks so no CU port bound.
// ---------------------------------------------------------------------------
__global__ __launch_bounds__(256) void text_proj_kernel(
    const float* __restrict__ text,     // [B, TEXT_DIM]
    const float* __restrict__ W_text,   // [HIDDEN, TEXT_DIM]
    const float* __restrict__ b_text,   // [HIDDEN]
    float* __restrict__ t_out)          // [B, HIDDEN]
{
    const int b    = blockIdx.x;
    const int lane = threadIdx.x & 63;
    const int hbase = blockIdx.y * 64 + (threadIdx.x >> 6) * 16;

    const f32x4* tx4 = (const f32x4*)(text + (size_t)b * TEXT_DIM);
    const f32x4 t0 = tx4[lane], t1 = tx4[lane + 64], t2 = tx4[lane + 128];

    #pragma unroll 2
    for (int i = 0; i < 16; ++i) {
        const int h = hbase + i;
        const f32x4* wr = (const f32x4*)(W_text + (size_t)h * TEXT_DIM);
        float s = dot4(t0, wr[lane]) + dot4(t1, wr[lane + 64])
                + dot4(t2, wr[lane + 128]);
        #pragma unroll
        for (int off = 32; off; off >>= 1)
            s += __shfl_xor(s, off, 64);
        if (lane == 0)
            t_out[(size_t)b * HIDDEN + h] = s + b_text[h];
    }
}

// ---------------------------------------------------------------------------
// Kernel B: v[b,d] = sum_h t[b,h]*W_patch[h,d]; bias[b] = t[b,:]·b_patch
// grid (32 b, 4 d-chunks) x 256; t[b] in LDS; 8 independent accumulators
// (R5's ILP tweak — the only tested change that strictly dominated).
// Each block reads only its 512 KB W_patch slice -> no port bound (the R6
// fused-prep lesson: redundant 2-3.5 MB per-block reads cost ~12 us).
// ---------------------------------------------------------------------------
__global__ __launch_bounds__(256) void fold_kernel(
    const float* __restrict__ t,        // [B, HIDDEN]
    const float* __restrict__ W_patch,  // [HIDDEN, PATCH_DIM]
    const float* __restrict__ b_patch,  // [HIDDEN]
    float* __restrict__ v,              // [B, PATCH_DIM]
    float* __restrict__ bias_out)       // [B]
{
    const int b   = blockIdx.x;
    const int dc  = blockIdx.y;
    const int tid = threadIdx.x;

    __shared__ float t_sh[HIDDEN];
    t_sh[tid]       = t[(size_t)b * HIDDEN + tid];
    t_sh[tid + 256] = t[(size_t)b * HIDDEN + tid + 256];
    __syncthreads();

    const int d = dc * 256 + tid;
    const float* wp = W_patch + d;

    float a0 = 0.f, a1 = 0.f, a2 = 0.f, a3 = 0.f;
    float a4 = 0.f, a5 = 0.f, a6 = 0.f, a7 = 0.f;
    #pragma unroll 4
    for (int h = 0; h < HIDDEN; h += 8) {
        a0 = fmaf(t_sh[h + 0], wp[(size_t)(h + 0) * PATCH_DIM], a0);
        a1 = fmaf(t_sh[h + 1], wp[(size_t)(h + 1) * PATCH_DIM], a1);
        a2 = fmaf(t_sh[h + 2], wp[(size_t)(h + 2) * PATCH_DIM], a2);
        a3 = fmaf(t_sh[h + 3], wp[(size_t)(h + 3) * PATCH_DIM], a3);
        a4 = fmaf(t_sh[h + 4], wp[(size_t)(h + 4) * PATCH_DIM], a4);
        a5 = fmaf(t_sh[h + 5], wp[(size_t)(h + 5) * PATCH_DIM], a5);
        a6 = fmaf(t_sh[h + 6], wp[(size_t)(h + 6) * PATCH_DIM], a6);
        a7 = fmaf(t_sh[h + 7], wp[(size_t)(h + 7) * PATCH_DIM], a7);
    }
    v[(size_t)b * PATCH_DIM + d] =
        ((a0 + a1) + (a2 + a3)) + ((a4 + a5) + (a6 + a7));

    if (dc == 0) {
        float partial = t_sh[tid] * b_patch[tid]
                      + t_sh[tid + 256] * b_patch[tid + 256];
        #pragma unroll
        for (int off = 32; off; off >>= 1)
            partial += __shfl_xor(partial, off, 64);
        __shared__ float wsum[4];
        if ((tid & 63) == 0) wsum[tid >> 6] = partial;
        __syncthreads();
        if (tid == 0)
            bias_out[b] = (wsum[0] + wsum[1]) + (wsum[2] + wsum[3]);
    }
}

// ---------------------------------------------------------------------------
// Kernel C (dominant, streams 512 MB of patches) — EXACT R2 (proven 112.5us;
// the four structural deviations each lost 9-29us):
//   scores[b,n] = patches[b,n,:] . v[b,:] + bias[b]
// 2048 blocks x 4 waves; wave owns 16 contiguous rows of one b; v[b] in 16
// regs; nontemporal loads (R5: removing nt cost ~14us — no-allocate protects
// L2 from the one-shot stream); compiler-scheduled 4-row groups at ~100 VGPR
// -> 5 waves/SIMD (R4: hand-pipeline at ~200 VGPR / 3 waves/SIMD lost 26%;
// occupancy is the precious resource for this latency-hiding pattern).
// ---------------------------------------------------------------------------
__global__ __launch_bounds__(256) void score_kernel(
    const float* __restrict__ patches,  // [B*N, PATCH_DIM]
    const float* __restrict__ v,        // [B, PATCH_DIM]
    const float* __restrict__ bias,     // [B]
    float* __restrict__ out)            // [B*N]
{
    const int lane = threadIdx.x & 63;
    const int g    = blockIdx.x * 4 + (threadIdx.x >> 6);  // 0..8191
    const int b    = g >> 8;          // 256 waves per b
    const int row0 = g << 4;          // 16 rows per wave

    const f32x4* vv = (const f32x4*)(v + (size_t)b * PATCH_DIM);
    const f32x4 v0 = vv[lane], v1 = vv[lane + 64],
                v2 = vv[lane + 128], v3 = vv[lane + 192];
    const float bs = bias[b];

    for (int i = 0; i < 16; i += 4) {
        const f32x4* p0 = (const f32x4*)(patches + (size_t)(row0 + i + 0) * PATCH_DIM);
        const f32x4* p1 = (const f32x4*)(patches + (size_t)(row0 + i + 1) * PATCH_DIM);
        const f32x4* p2 = (const f32x4*)(patches + (size_t)(row0 + i + 2) * PATCH_DIM);
        const f32x4* p3 = (const f32x4*)(patches + (size_t)(row0 + i + 3) * PATCH_DIM);

        f32x4 a00 = __builtin_nontemporal_load(p0 + lane);
        f32x4 a01 = __builtin_nontemporal_load(p0 + lane + 64);
        f32x4 a02 = __builtin_nontemporal_load(p0 + lane + 128);
        f32x4 a03 = __builtin_nontemporal_load(p0 + lane + 192);
        f32x4 a10 = __builtin_nontemporal_load(p1 + lane);
        f32x4 a11 = __builtin_nontemporal_load(p1 + lane + 64);
        f32x4 a12 = __builtin_nontemporal_load(p1 + lane + 128);
        f32x4 a13 = __builtin_nontemporal_load(p1 + lane + 192);
        f32x4 a20 = __builtin_nontemporal_load(p2 + lane);
        f32x4 a21 = __builtin_nontemporal_load(p2 + lane + 64);
        f32x4 a22 = __builtin_nontemporal_load(p2 + lane + 128);
        f32x4 a23 = __builtin_nontemporal_load(p2 + lane + 192);
        f32x4 a30 = __builtin_nontemporal_load(p3 + lane);
        f32x4 a31 = __builtin_nontemporal_load(p3 + lane + 64);
        f32x4 a32 = __builtin_nontemporal_load(p3 + lane + 128);
        f32x4 a33 = __builtin_nontemporal_load(p3 + lane + 192);

        float s0 = dot4(a00, v0) + dot4(a01, v1) + dot4(a02, v2) + dot4(a03, v3);
        float s1 = dot4(a10, v0) + dot4(a11, v1) + dot4(a12, v2) + dot4(a13, v3);
        float s2 = dot4(a20, v0) + dot4(a21, v1) + dot4(a22, v2) + dot4(a23, v3);
        float s3 = dot4(a30, v0) + dot4(a31, v1) + dot4(a32, v2) + dot4(a33, v3);

        // 4 independent butterfly chains, interleaved to hide shfl latency
        #pragma unroll
        for (int off = 32; off; off >>= 1) {
            s0 += __shfl_xor(s0, off, 64);
            s1 += __shfl_xor(s1, off, 64);
            s2 += __shfl_xor(s2, off, 64);
            s3 += __shfl_xor(s3, off, 64);
        }

        if (lane == 0) {
            f32x4 o = { s0 + bs, s1 + bs, s2 + bs, s3 + bs };
            *(f32x4*)(out + row0 + i) = o;
        }
    }
}

extern "C" void kernel_launch(void* const* d_in, const int* in_sizes, int n_in,
                              void* d_out, int out_size, void* d_ws, size_t ws_size,
                              hipStream_t stream) {
    const float* patches = (const float*)d_in[0];  // [B, N, PATCH_DIM]
    const float* text    = (const float*)d_in[1];  // [B, TEXT_DIM]
    const float* W_patch = (const float*)d_in[2];  // [HIDDEN, PATCH_DIM]
    const float* b_patch = (const float*)d_in[3];  // [HIDDEN]
    const float* W_text  = (const float*)d_in[4];  // [HIDDEN, TEXT_DIM]
    const float* b_text  = (const float*)d_in[5];  // [HIDDEN]
    float* out = (float*)d_out;                    // [B, N]

    // Workspace layout (floats): t [B*HIDDEN], v [B*PATCH_DIM], bias [B]
    float* t_ws    = (float*)d_ws;
    float* v_ws    = t_ws + B_DIM * HIDDEN;
    float* bias_ws = v_ws + B_DIM * PATCH_DIM;

    text_proj_kernel<<<dim3(B_DIM, 8), 256, 0, stream>>>(text, W_text, b_text, t_ws);
    fold_kernel<<<dim3(B_DIM, 4), 256, 0, stream>>>(t_ws, W_patch, b_patch, v_ws, bias_ws);
    score_kernel<<<2048, 256, 0, stream>>>(patches, v_ws, bias_ws, out);
}